// Round 5
// baseline (109.648 us; speedup 1.0000x reference)
//
#include <hip/hip_runtime.h>
#include <math.h>

#define S 4096
#define B 16
#define R 8             // attention rows per wave

// ---------------------------------------------------------------------------
// Fused QKV skinny GEMM — pure streaming, no LDS, no barriers.
// Grid: 1536 blocks = 3 mats x 512 groups(8 rows x 16 batches).
// Wave = 4 W-rows x 8 batches (acc[4][8]); W is double-buffered in two NAMED
// float4x4 register sets, processing 2 chunks (2x256 cols) per loop iter so
// buffer roles are compile-time static (runtime-indexed arrays -> scratch).
// While chunk c computes, chunk c+1's 4 KB of W loads are in flight; with
// ~16 waves/CU that sustains >>30 KB in-flight per CU (Little's law for
// 6.3 TB/s @ ~900cy). x (256 KB) is read straight from L2 per iteration.
// ---------------------------------------------------------------------------
__global__ __launch_bounds__(256, 4) void qkv_kernel(
    const float* __restrict__ x,
    const float* __restrict__ Wq, const float* __restrict__ bq,
    const float* __restrict__ Wk, const float* __restrict__ bk,
    const float* __restrict__ Wv, const float* __restrict__ bv,
    float* __restrict__ q, float* __restrict__ k, float* __restrict__ v)
{
    const int tid  = threadIdx.x;
    const int lane = tid & 63;
    const int wave = tid >> 6;
    const int bx   = blockIdx.x;        // 0..1535
    const int mat  = bx >> 9;           // 0:q 1:k 2:v
    const int og   = bx & 511;          // 8-row group

    const float* W    = (mat == 0) ? Wq : (mat == 1) ? Wk : Wv;
    const float* bias = (mat == 0) ? bq : (mat == 1) ? bk : bv;
    float*       out  = (mat == 0) ? q  : (mat == 1) ? k  : v;
    const int o0  = og * 8 + (wave >> 1) * 4;   // this wave's 4 W-rows
    const int bb0 = (wave & 1) * 8;             // this wave's 8 batches
    const float* Wp = W + (size_t)o0 * S + lane * 4;   // lane-resolved base
    const float* xp = x + (size_t)bb0 * S + lane * 4;

    float acc[4][8];
    #pragma unroll
    for (int r = 0; r < 4; ++r)
        #pragma unroll
        for (int bi = 0; bi < 8; ++bi) acc[r][bi] = 0.f;

    // prologue: chunk 0 -> buffer A
    float4 wa0 = *(const float4*)&Wp[0 * S];
    float4 wa1 = *(const float4*)&Wp[1 * S];
    float4 wa2 = *(const float4*)&Wp[2 * S];
    float4 wa3 = *(const float4*)&Wp[3 * S];

#define QKV_COMPUTE(c, W0, W1, W2, W3)                                   \
    {                                                                    \
        const int sl = (c) * 256;                                        \
        _Pragma("unroll")                                                \
        for (int bi = 0; bi < 8; ++bi) {                                 \
            float4 xv = *(const float4*)&xp[(size_t)bi * S + sl];        \
            acc[0][bi] = fmaf(W0.x, xv.x, acc[0][bi]);                   \
            acc[0][bi] = fmaf(W0.y, xv.y, acc[0][bi]);                   \
            acc[0][bi] = fmaf(W0.z, xv.z, acc[0][bi]);                   \
            acc[0][bi] = fmaf(W0.w, xv.w, acc[0][bi]);                   \
            acc[1][bi] = fmaf(W1.x, xv.x, acc[1][bi]);                   \
            acc[1][bi] = fmaf(W1.y, xv.y, acc[1][bi]);                   \
            acc[1][bi] = fmaf(W1.z, xv.z, acc[1][bi]);                   \
            acc[1][bi] = fmaf(W1.w, xv.w, acc[1][bi]);                   \
            acc[2][bi] = fmaf(W2.x, xv.x, acc[2][bi]);                   \
            acc[2][bi] = fmaf(W2.y, xv.y, acc[2][bi]);                   \
            acc[2][bi] = fmaf(W2.z, xv.z, acc[2][bi]);                   \
            acc[2][bi] = fmaf(W2.w, xv.w, acc[2][bi]);                   \
            acc[3][bi] = fmaf(W3.x, xv.x, acc[3][bi]);                   \
            acc[3][bi] = fmaf(W3.y, xv.y, acc[3][bi]);                   \
            acc[3][bi] = fmaf(W3.z, xv.z, acc[3][bi]);                   \
            acc[3][bi] = fmaf(W3.w, xv.w, acc[3][bi]);                   \
        }                                                                \
    }

    #pragma unroll 1
    for (int cc = 0; cc < 8; ++cc) {
        const int c0 = 2 * cc;
        // issue chunk c0+1 -> buffer B (always valid: c0+1 <= 15)
        float4 wb0 = *(const float4*)&Wp[0 * S + (c0 + 1) * 256];
        float4 wb1 = *(const float4*)&Wp[1 * S + (c0 + 1) * 256];
        float4 wb2 = *(const float4*)&Wp[2 * S + (c0 + 1) * 256];
        float4 wb3 = *(const float4*)&Wp[3 * S + (c0 + 1) * 256];
        QKV_COMPUTE(c0, wa0, wa1, wa2, wa3);
        // issue chunk c0+2 -> buffer A (clamp: last iter reloads chunk 15)
        const int cn = (c0 + 2 < 16) ? (c0 + 2) : 15;
        wa0 = *(const float4*)&Wp[0 * S + cn * 256];
        wa1 = *(const float4*)&Wp[1 * S + cn * 256];
        wa2 = *(const float4*)&Wp[2 * S + cn * 256];
        wa3 = *(const float4*)&Wp[3 * S + cn * 256];
        QKV_COMPUTE(c0 + 1, wb0, wb1, wb2, wb3);
    }
#undef QKV_COMPUTE

    // cross-lane reduction; lane (r*8+bi) writes output (bb0+bi, o0+r)
    #pragma unroll
    for (int r = 0; r < 4; ++r) {
        #pragma unroll
        for (int bi = 0; bi < 8; ++bi) {
            float s = acc[r][bi];
            #pragma unroll
            for (int off = 32; off; off >>= 1) s += __shfl_xor(s, off, 64);
            if (lane == r * 8 + bi)
                out[(size_t)(bb0 + bi) * S + o0 + r] = s + bias[o0 + r];
        }
    }
}

// ---------------------------------------------------------------------------
// Inclusive prefix max/min of k per batch row. 16 blocks x 256 threads.
// ---------------------------------------------------------------------------
__global__ __launch_bounds__(256) void scan_kernel(
    const float* __restrict__ k,
    float* __restrict__ rmax, float* __restrict__ rmin)
{
    __shared__ float smax[256], smin[256];
    const int b = blockIdx.x, t = threadIdx.x;
    const float* kb = k + b * S;

    float seg[16];
    float lmax = -INFINITY, lmin = INFINITY;
    #pragma unroll
    for (int e = 0; e < 16; ++e) {
        seg[e] = kb[t * 16 + e];
        lmax = fmaxf(lmax, seg[e]);
        lmin = fminf(lmin, seg[e]);
    }
    smax[t] = lmax; smin[t] = lmin;
    __syncthreads();
    for (int off = 1; off < 256; off <<= 1) {
        float vx = (t >= off) ? smax[t - off] : -INFINITY;
        float vn = (t >= off) ? smin[t - off] :  INFINITY;
        __syncthreads();
        smax[t] = fmaxf(smax[t], vx);
        smin[t] = fminf(smin[t], vn);
        __syncthreads();
    }
    float runmax = (t > 0) ? smax[t - 1] : -INFINITY;
    float runmin = (t > 0) ? smin[t - 1] :  INFINITY;
    #pragma unroll
    for (int e = 0; e < 16; ++e) {
        runmax = fmaxf(runmax, seg[e]);
        runmin = fminf(runmin, seg[e]);
        rmax[b * S + t * 16 + e] = runmax;
        rmin[b * S + t * 16 + e] = runmin;
    }
}

// ---------------------------------------------------------------------------
// d=1 causal attention, single pass (row max known from prefix scan).
// Wave handles R=8 consecutive rows of one batch, sharing k/v loads.
// ---------------------------------------------------------------------------
__global__ __launch_bounds__(256) void attn_kernel(
    const float* __restrict__ q, const float* __restrict__ k,
    const float* __restrict__ v,
    const float* __restrict__ rmax, const float* __restrict__ rmin,
    float* __restrict__ out)
{
    const int tid = threadIdx.x, lane = tid & 63, wave = tid >> 6;
    const int task = blockIdx.x * 4 + wave;     // 0..8191
    const int b    = task & 15;
    const int rbi  = task >> 4;                 // 0..511
    const int i0   = (511 - rbi) * R;           // descending: big rows first
    const float* kb = k + b * S;
    const float* vb = v + b * S;
    const float LOG2E = 1.4426950408889634f;

    float a[R], cc[R], den[R], num[R];
    #pragma unroll
    for (int r = 0; r < R; ++r) {
        float qi = q[b * S + i0 + r];
        float m  = (qi >= 0.f) ? qi * rmax[b * S + i0 + r]
                               : qi * rmin[b * S + i0 + r];
        a[r]  = qi * LOG2E;
        cc[r] = -m * LOG2E;
        den[r] = 0.f; num[r] = 0.f;
    }

    const int nfull = (i0 + 1) >> 8;            // full 256-wide chunks
    #pragma unroll 1
    for (int it = 0; it < nfull; ++it) {
        const int j = it * 256 + lane * 4;
        float4 k4 = *(const float4*)&kb[j];
        float4 v4 = *(const float4*)&vb[j];
        #pragma unroll
        for (int jj = 0; jj < 4; ++jj) {
            float kx = (&k4.x)[jj], vx = (&v4.x)[jj];
            #pragma unroll
            for (int r = 0; r < R; ++r) {
                float e = exp2f(fmaf(a[r], kx, cc[r]));
                den[r] += e;
                num[r] = fmaf(e, vx, num[r]);
            }
        }
    }
    // masked tail
    const int imax = i0 + R - 1;
    for (int j = nfull * 256 + lane; j <= imax; j += 64) {
        float kx = kb[j], vx = vb[j];
        #pragma unroll
        for (int r = 0; r < R; ++r) {
            float e = (j <= i0 + r) ? exp2f(fmaf(a[r], kx, cc[r])) : 0.f;
            den[r] += e;
            num[r] = fmaf(e, vx, num[r]);
        }
    }

    #pragma unroll
    for (int r = 0; r < R; ++r) {
        float d = den[r], n = num[r];
        #pragma unroll
        for (int off = 32; off; off >>= 1) {
            d += __shfl_xor(d, off, 64);
            n += __shfl_xor(n, off, 64);
        }
        if (lane == r) out[b * S + i0 + r] = n / d;
    }
}

extern "C" void kernel_launch(void* const* d_in, const int* in_sizes, int n_in,
                              void* d_out, int out_size, void* d_ws, size_t ws_size,
                              hipStream_t stream) {
    const float* x  = (const float*)d_in[0];
    const float* Wq = (const float*)d_in[1];
    const float* bq = (const float*)d_in[2];
    const float* Wk = (const float*)d_in[3];
    const float* bk = (const float*)d_in[4];
    const float* Wv = (const float*)d_in[5];
    const float* bv = (const float*)d_in[6];
    float* out = (float*)d_out;

    float* ws   = (float*)d_ws;
    float* q    = ws;                // 16*4096
    float* k    = ws + 65536;
    float* v    = ws + 131072;
    float* rmax = ws + 196608;
    float* rmin = ws + 262144;       // total 1.25 MB scratch

    qkv_kernel<<<1536, 256, 0, stream>>>(x, Wq, bq, Wk, bk, Wv, bv, q, k, v);
    scan_kernel<<<16, 256, 0, stream>>>(k, rmax, rmin);
    attn_kernel<<<2048, 256, 0, stream>>>(q, k, v, rmax, rmin, out);
}